// Round 5
// baseline (451.916 us; speedup 1.0000x reference)
//
#include <hip/hip_runtime.h>
#include <stdint.h>

// ---------------------------------------------------------------------------
// EdgeNodeGCN on MI355X (gfx950). Inputs fp32 (auto-detected, bf16 fallback),
// edge_index int32/int64 auto-detected, OUTPUT fp32 (reference returns
// jnp.float32; rounds 0-4 wrote bf16 -> upper half of d_out stayed 0 ->
// deterministic absmax 0.9488 at unwritten elements).
// Factorization:
//   P[n]  = x[n] @ (Wa - Wb) + b_edge   (Wa = W_edge[0:128], Wb = W_edge[128:256])
//   Q[n]  = x[n] @ Wb
//   msg(e)= relu(P[dst] + Q[src]);  edge_agg[d] = sum msg  (pull via CSR)
//   XA[d] = sum_{e->d} x[src]           (segment_sum commutes with @W_node)
//   nodes = relu(XA @ W_node + b_node); edges = relu(edge_agg @ W_ed + b_ed)
//   out   = sigmoid(relu([nodes|edges] @ W_f1 + b_f1) @ W_f2 + b_f2)
//
// CSR build: atomic segment allocation (segment order nondeterministic,
// contents exact).
//
// ws layout (78.2 MB):
//   xb bf16[N][128]; WE2 bf16[128][512]=[Wa-Wb|Wb]; Wn[128][256]; Wd[256][128];
//   Wf1[384][32]; T bf16[N][512] (P|Q -> EA over P -> nodes 0-255, edges 384-511);
//   XA bf16[N][128]; deg/cursor int[N]; start int[N]; csr u16[E];
//   flags int[4]: [0] x-is-fp32, [1] ei-is-int32, [2] atomic cursor
// ---------------------------------------------------------------------------

typedef short short8 __attribute__((ext_vector_type(8)));
typedef float f32x4 __attribute__((ext_vector_type(4)));
typedef float float4v __attribute__((ext_vector_type(4)));
typedef unsigned short us4 __attribute__((ext_vector_type(4)));
typedef unsigned short us2 __attribute__((ext_vector_type(2)));

__device__ inline float bf2f(unsigned short h) {
    union { unsigned int u; float f; } v;
    v.u = ((unsigned int)h) << 16;
    return v.f;
}
__device__ inline unsigned short f2bf(float f) {
    union { float f; unsigned int u; } v;
    v.f = f;
    unsigned int r = v.u + 0x7FFFu + ((v.u >> 16) & 1u);  // RNE
    return (unsigned short)(r >> 16);
}
// dual-dtype scalar load: isf32 ? fp32[i] : bf16[i]
__device__ inline float ldf(const void* p, int i, int isf32) {
    return isf32 ? ((const float*)p)[i] : bf2f(((const unsigned short*)p)[i]);
}

// ---- probe x dtype: low u16 of each u32 looks like a bf16 of N(0,1)? ------
__global__ __launch_bounds__(1024) void k_probe_x(const unsigned int* __restrict__ x,
                                                  int* __restrict__ flags) {
    __shared__ int sh[1024];
    int tid = threadIdx.x;
    int m = 0;
    for (int j = 0; j < 4; ++j) {
        unsigned int w = x[tid * 4 + j];
        int e8 = (w >> 7) & 0xFF;                 // bf16 exponent of low half
        m += (e8 >= 113 && e8 <= 142);
    }
    sh[tid] = m;
    __syncthreads();
    for (int s = 512; s > 0; s >>= 1) {
        if (tid < s) sh[tid] += sh[tid + s];
        __syncthreads();
    }
    if (tid == 0) flags[0] = (sh[0] > 2048) ? 0 : 1;   // 1 = fp32
}

// ---- probe edge_index dtype: any nonzero odd int32 word => int32 ----------
__global__ void k_probe_ei(const int* __restrict__ ei, int* __restrict__ flags, int half) {
    int i = blockIdx.x * 256 + threadIdx.x;
    int nz = (i < half) ? (ei[2 * i + 1] != 0) : 0;
    unsigned long long b = __ballot(nz);
    if ((threadIdx.x & 63) == 0 && b) atomicOr(&flags[1], 1);  // 1 = int32
}

// ---- canonicalize x -> bf16 ----------------------------------------------
__global__ __launch_bounds__(256) void k_convert_x(const void* __restrict__ x,
                                                   unsigned short* __restrict__ xb,
                                                   const int* __restrict__ flags,
                                                   int quads) {  // quads = N*128/4
    int i = blockIdx.x * 256 + threadIdx.x;
    if (i >= quads) return;
    us4 o;
    if (flags[0]) {
        float4v v = ((const float4v*)x)[i];
        for (int j = 0; j < 4; ++j) o[j] = f2bf(v[j]);
    } else {
        o = ((const us4*)x)[i];
    }
    ((us4*)xb)[i] = o;
}

// ---- canonicalize weights (WE2 fold, Wn, Wd, Wf1) -------------------------
__global__ __launch_bounds__(256) void k_convert_w(
    const void* __restrict__ W_edge, const void* __restrict__ W_node,
    const void* __restrict__ W_ed, const void* __restrict__ W_f1,
    unsigned short* __restrict__ WE2, unsigned short* __restrict__ Wn,
    unsigned short* __restrict__ Wd, unsigned short* __restrict__ Wf1,
    const int* __restrict__ flags) {
    int i = blockIdx.x * 256 + threadIdx.x;
    int isf = flags[0];
    if (i < 65536) {                         // WE2 [128][512]
        int k = i >> 9, c = i & 511;
        float v;
        if (c < 256) v = ldf(W_edge, k * 256 + c, isf) - ldf(W_edge, (k + 128) * 256 + c, isf);
        else         v = ldf(W_edge, (k + 128) * 256 + (c - 256), isf);
        WE2[i] = f2bf(v);
    } else if (i < 65536 + 32768) {          // Wn flat [128*256]
        int j = i - 65536;
        Wn[j] = f2bf(ldf(W_node, j, isf));
    } else if (i < 65536 + 65536) {          // Wd flat [256*128]
        int j = i - 65536 - 32768;
        Wd[j] = f2bf(ldf(W_ed, j, isf));
    } else if (i < 65536 + 65536 + 12288) {  // Wf1 flat [384*32]
        int j = i - 65536 - 65536;
        Wf1[j] = f2bf(ldf(W_f1, j, isf));
    }
}

// ---- CSR build ------------------------------------------------------------
__global__ void k_hist(const int* __restrict__ ei, const int* __restrict__ flags,
                       int* __restrict__ deg, int E, int N) {
    int i = blockIdx.x * 256 + threadIdx.x;
    if (i >= E) return;
    int d = flags[1] ? ei[E + i] : ei[2 * (E + i)];
    if ((unsigned)d < (unsigned)N) atomicAdd(&deg[d], 1);
}

// race-free segment allocation: start[n] = fetch_add(total, deg[n]).
__global__ void k_assign(int* __restrict__ deg_cursor, int* __restrict__ startv,
                         int* __restrict__ counter, int N) {
    int n = blockIdx.x * 256 + threadIdx.x;
    if (n >= N) return;
    int d = deg_cursor[n];
    int s = atomicAdd(counter, d);
    startv[n] = s;
    deg_cursor[n] = s;   // becomes the scatter cursor
}

__global__ void k_scatter(const int* __restrict__ ei, const int* __restrict__ flags,
                          int* __restrict__ cursor, unsigned short* __restrict__ csr_src,
                          int E, int N) {
    int i = blockIdx.x * 256 + threadIdx.x;
    if (i >= E) return;
    int s, d;
    if (flags[1]) { s = ei[i]; d = ei[E + i]; }
    else          { s = ei[2 * i]; d = ei[2 * (E + i)]; }
    if ((unsigned)d >= (unsigned)N || (unsigned)s >= (unsigned)N) return;
    int pos = atomicAdd(&cursor[d], 1);
    if ((unsigned)pos < (unsigned)E) csr_src[pos] = (unsigned short)s;
}

// ---- GEMM1: T = xb @ WE2  (P cols get +b_edge) ----------------------------
__global__ __launch_bounds__(512) void k_gemm1(
    const unsigned short* __restrict__ xb,     // [N][128] bf16
    const unsigned short* __restrict__ WE2,    // [128][512] bf16
    const void* __restrict__ b_edge,           // [256] fp32/bf16
    const int* __restrict__ flags,
    unsigned short* __restrict__ T,            // [N][512]
    int row_tiles)
{
    const int lane = threadIdx.x & 63;
    const int wave = threadIdx.x >> 6;
    const int quad = lane >> 4;
    const int col16 = lane & 15;
    const int strip = blockIdx.y * 8 + wave;    // 0..31
    const int col = strip * 16 + col16;         // 0..511
    const int isf = flags[0];

    float bias = (col < 256) ? ldf(b_edge, col, isf) : 0.f;

    short8 bf[4];
    for (int ks = 0; ks < 4; ++ks) {
        short8 b;
        for (int j = 0; j < 8; ++j) {
            int k = ks * 32 + quad * 8 + j;
            b[j] = (short)WE2[k * 512 + col];
        }
        bf[ks] = b;
    }

    for (int t = 0; t < 8; ++t) {
        int tile = blockIdx.x * 8 + t;
        if (tile >= row_tiles) break;
        int r0 = tile * 16;
        f32x4 acc = {0.f, 0.f, 0.f, 0.f};
        const unsigned short* ap = xb + (size_t)(r0 + col16) * 128 + quad * 8;
        for (int ks = 0; ks < 4; ++ks) {
            short8 a = *(const short8*)(ap + ks * 32);
            acc = __builtin_amdgcn_mfma_f32_16x16x32_bf16(a, bf[ks], acc, 0, 0, 0);
        }
        int orow = r0 + quad * 4;
        for (int r = 0; r < 4; ++r)
            T[(size_t)(orow + r) * 512 + col] = f2bf(acc[r] + bias);
    }
}

// ---- Gather: one wave per node; EA over P slot, XA from xb ----------------
__global__ __launch_bounds__(256) void k_gather(
    unsigned short* __restrict__ T,          // [N][512]
    const unsigned short* __restrict__ xb,   // [N][128]
    unsigned short* __restrict__ XA,         // [N][128]
    const int* __restrict__ start, const int* __restrict__ endp,
    const unsigned short* __restrict__ csr_src, int N, int E)
{
    int wave = threadIdx.x >> 6;
    int lane = threadIdx.x & 63;
    int n = blockIdx.x * 4 + wave;
    if (n >= N) return;
    int c4 = lane * 4;
    int c2 = lane * 2;

    us4 pv = *(const us4*)(T + (size_t)n * 512 + c4);
    float p[4], aE[4] = {0, 0, 0, 0}, aX[2] = {0, 0};
    for (int j = 0; j < 4; ++j) p[j] = bf2f(pv[j]);

    int b = start[n], e = endp[n];
    if (b < 0) b = 0;
    if (e > E) e = E;
    for (int i = b; i < e; ++i) {
        int s = csr_src[i];
        if (s >= N) continue;
        const unsigned short* tb = T + (size_t)s * 512;
        us4 qv = *(const us4*)(tb + 256 + c4);
        us2 xv = *(const us2*)(xb + (size_t)s * 128 + c2);
        for (int j = 0; j < 4; ++j)
            aE[j] += fmaxf(p[j] + bf2f(qv[j]), 0.f);
        aX[0] += bf2f(xv[0]);
        aX[1] += bf2f(xv[1]);
    }
    us4 ev;
    for (int j = 0; j < 4; ++j) ev[j] = f2bf(aE[j]);
    *(us4*)(T + (size_t)n * 512 + c4) = ev;            // EA over own P: safe
    us2 xo; xo[0] = f2bf(aX[0]); xo[1] = f2bf(aX[1]);
    *(us2*)(XA + (size_t)n * 128 + c2) = xo;
}

// ---- GEMM2: edges = relu(EA @ Wd + b_ed) -> T cols 384..511 ---------------
__global__ __launch_bounds__(512) void k_gemm2(
    unsigned short* __restrict__ T,           // reads cols 0-255 (EA)
    const unsigned short* __restrict__ Wd,    // [256][128] bf16
    const void* __restrict__ b_ed,            // [128]
    const int* __restrict__ flags,
    int row_tiles)
{
    const int lane = threadIdx.x & 63;
    const int wave = threadIdx.x >> 6;
    const int quad = lane >> 4;
    const int col16 = lane & 15;
    const int col = wave * 16 + col16;        // 0..127

    short8 bf[8];
    for (int ks = 0; ks < 8; ++ks) {
        short8 b;
        for (int j = 0; j < 8; ++j) {
            int k = ks * 32 + quad * 8 + j;
            b[j] = (short)Wd[k * 128 + col];
        }
        bf[ks] = b;
    }
    float bias = ldf(b_ed, col, flags[0]);

    for (int t = 0; t < 8; ++t) {
        int tile = blockIdx.x * 8 + t;
        if (tile >= row_tiles) break;
        int r0 = tile * 16;
        f32x4 acc = {0.f, 0.f, 0.f, 0.f};
        const unsigned short* ap = T + (size_t)(r0 + col16) * 512 + quad * 8;
        for (int ks = 0; ks < 8; ++ks) {
            short8 a = *(const short8*)(ap + ks * 32);
            acc = __builtin_amdgcn_mfma_f32_16x16x32_bf16(a, bf[ks], acc, 0, 0, 0);
        }
        int orow = r0 + quad * 4;
        for (int r = 0; r < 4; ++r)
            T[(size_t)(orow + r) * 512 + 384 + col] = f2bf(fmaxf(acc[r] + bias, 0.f));
    }
}

// ---- GEMM-node: nodes = relu(XA @ Wn + b_node) -> T cols 0..255 -----------
__global__ __launch_bounds__(512) void k_gemm_node(
    const unsigned short* __restrict__ XA,      // [N][128]
    const unsigned short* __restrict__ Wn,      // [128][256] bf16
    const void* __restrict__ b_node,            // [256]
    const int* __restrict__ flags,
    unsigned short* __restrict__ T, int row_tiles)
{
    const int lane = threadIdx.x & 63;
    const int wave = threadIdx.x >> 6;
    const int quad = lane >> 4;
    const int col16 = lane & 15;
    const int strip = blockIdx.y * 8 + wave;    // 0..15
    const int col = strip * 16 + col16;         // 0..255

    short8 bf[4];
    for (int ks = 0; ks < 4; ++ks) {
        short8 b;
        for (int j = 0; j < 8; ++j) {
            int k = ks * 32 + quad * 8 + j;
            b[j] = (short)Wn[k * 256 + col];
        }
        bf[ks] = b;
    }
    float bias = ldf(b_node, col, flags[0]);

    for (int t = 0; t < 8; ++t) {
        int tile = blockIdx.x * 8 + t;
        if (tile >= row_tiles) break;
        int r0 = tile * 16;
        f32x4 acc = {0.f, 0.f, 0.f, 0.f};
        const unsigned short* ap = XA + (size_t)(r0 + col16) * 128 + quad * 8;
        for (int ks = 0; ks < 4; ++ks) {
            short8 a = *(const short8*)(ap + ks * 32);
            acc = __builtin_amdgcn_mfma_f32_16x16x32_bf16(a, bf[ks], acc, 0, 0, 0);
        }
        int orow = r0 + quad * 4;
        for (int r = 0; r < 4; ++r)
            T[(size_t)(orow + r) * 512 + col] = f2bf(fmaxf(acc[r] + bias, 0.f));
    }
}

// ---- Final: out = sigmoid(relu(h@W_f1+b_f1)@W_f2+b_f2), h=[nodes|edges] ---
// OUTPUT IS FP32 (reference returns jnp.float32).
__global__ __launch_bounds__(64) void k_final(
    const unsigned short* __restrict__ T,
    const unsigned short* __restrict__ Wf1,   // [384][32] bf16
    const void* __restrict__ b_f1,            // [32]
    const void* __restrict__ W_f2,            // [32]
    const void* __restrict__ b_f2,            // [1]
    const int* __restrict__ flags,
    float* __restrict__ out, int row_tiles)
{
    const int lane = threadIdx.x & 63;
    const int quad = lane >> 4;
    const int col16 = lane & 15;
    const int isf = flags[0];

    short8 bfa[12], bfb[12];
    for (int ks = 0; ks < 12; ++ks) {
        short8 a, b;
        for (int j = 0; j < 8; ++j) {
            int k = ks * 32 + quad * 8 + j;
            a[j] = (short)Wf1[k * 32 + col16];
            b[j] = (short)Wf1[k * 32 + 16 + col16];
        }
        bfa[ks] = a; bfb[ks] = b;
    }
    float f1a = ldf(b_f1, col16, isf), f1b = ldf(b_f1, 16 + col16, isf);
    float w2a = ldf(W_f2, col16, isf), w2b = ldf(W_f2, 16 + col16, isf);
    float b2 = ldf(b_f2, 0, isf);

    for (int t = 0; t < 8; ++t) {
        int tile = blockIdx.x * 8 + t;
        if (tile >= row_tiles) break;
        int r0 = tile * 16;
        f32x4 acc0 = {0, 0, 0, 0}, acc1 = {0, 0, 0, 0};
        const unsigned short* ap = T + (size_t)(r0 + col16) * 512;
        for (int ks = 0; ks < 12; ++ks) {
            int off = (ks < 8) ? ks * 32 : ks * 32 + 128;  // nodes | edges slot
            short8 a = *(const short8*)(ap + off + quad * 8);
            acc0 = __builtin_amdgcn_mfma_f32_16x16x32_bf16(a, bfa[ks], acc0, 0, 0, 0);
            acc1 = __builtin_amdgcn_mfma_f32_16x16x32_bf16(a, bfb[ks], acc1, 0, 0, 0);
        }
        float s[4];
        for (int r = 0; r < 4; ++r)
            s[r] = fmaxf(acc0[r] + f1a, 0.f) * w2a + fmaxf(acc1[r] + f1b, 0.f) * w2b;
        for (int m = 1; m < 16; m <<= 1)
            for (int r = 0; r < 4; ++r) s[r] += __shfl_xor(s[r], m, 64);
        if (col16 == 0) {
            int orow = r0 + quad * 4;
            for (int r = 0; r < 4; ++r) {
                float v = s[r] + b2;
                out[orow + r] = 1.f / (1.f + __expf(-v));   // fp32 store
            }
        }
    }
}

extern "C" void kernel_launch(void* const* d_in, const int* in_sizes, int n_in,
                              void* d_out, int out_size, void* d_ws, size_t ws_size,
                              hipStream_t stream) {
    const void* x      = d_in[0];
    const int*  ei     = (const int*)d_in[1];
    // d_in[2] = e (unused)
    const void* W_node = d_in[3];
    const void* b_node = d_in[4];
    const void* W_edge = d_in[5];
    const void* b_edge = d_in[6];
    const void* W_ed   = d_in[7];
    const void* b_ed   = d_in[8];
    const void* W_f1   = d_in[9];
    const void* b_f1   = d_in[10];
    const void* W_f2   = d_in[11];
    const void* b_f2   = d_in[12];

    const int N = in_sizes[0] / 128;
    const int E = in_sizes[1] / 2;

    char* ws = (char*)d_ws;
    size_t off = 0;
    auto alloc = [&](size_t bytes) { size_t o = off; off += (bytes + 255) & ~(size_t)255; return o; };
    unsigned short* xb  = (unsigned short*)(ws + alloc((size_t)N * 128 * 2));
    unsigned short* WE2 = (unsigned short*)(ws + alloc(128 * 512 * 2));
    unsigned short* Wn  = (unsigned short*)(ws + alloc(128 * 256 * 2));
    unsigned short* Wd  = (unsigned short*)(ws + alloc(256 * 128 * 2));
    unsigned short* Wf1 = (unsigned short*)(ws + alloc(384 * 32 * 2));
    unsigned short* T   = (unsigned short*)(ws + alloc((size_t)N * 512 * 2));
    unsigned short* XA  = (unsigned short*)(ws + alloc((size_t)N * 128 * 2));
    int* deg_cursor     = (int*)(ws + alloc((size_t)N * 4));
    int* startv         = (int*)(ws + alloc((size_t)N * 4));
    unsigned short* csr = (unsigned short*)(ws + alloc((size_t)E * 2));
    int* flags          = (int*)(ws + alloc(16));

    const int row_tiles  = (N + 15) / 16;
    const int row_groups = (row_tiles + 7) / 8;

    hipMemsetAsync(deg_cursor, 0, (size_t)N * 4, stream);
    hipMemsetAsync(flags, 0, 16, stream);
    k_probe_x<<<1, 1024, 0, stream>>>((const unsigned int*)x, flags);
    k_probe_ei<<<(E + 255) / 256, 256, 0, stream>>>(ei, flags, E);
    k_convert_x<<<((N * 128 / 4) + 255) / 256, 256, 0, stream>>>(x, xb, flags, N * 128 / 4);
    k_convert_w<<<(143360 + 255) / 256, 256, 0, stream>>>(W_edge, W_node, W_ed, W_f1,
                                                          WE2, Wn, Wd, Wf1, flags);
    k_hist<<<(E + 255) / 256, 256, 0, stream>>>(ei, flags, deg_cursor, E, N);
    k_assign<<<(N + 255) / 256, 256, 0, stream>>>(deg_cursor, startv, &flags[2], N);
    k_scatter<<<(E + 255) / 256, 256, 0, stream>>>(ei, flags, deg_cursor, csr, E, N);
    k_gemm1<<<dim3(row_groups, 4), 512, 0, stream>>>(xb, WE2, b_edge, flags, T, row_tiles);
    k_gather<<<(N + 3) / 4, 256, 0, stream>>>(T, xb, XA, startv, deg_cursor, csr, N, E);
    k_gemm2<<<row_groups, 512, 0, stream>>>(T, Wd, b_ed, flags, row_tiles);
    k_gemm_node<<<dim3(row_groups, 2), 512, 0, stream>>>(XA, Wn, b_node, flags, T, row_tiles);
    k_final<<<row_groups, 64, 0, stream>>>(T, Wf1, b_f1, W_f2, b_f2, flags,
                                           (float*)d_out, row_tiles);
}

// Round 6
// 364.318 us; speedup vs baseline: 1.2404x; 1.2404x over previous
//
#include <hip/hip_runtime.h>
#include <stdint.h>

// ---------------------------------------------------------------------------
// EdgeNodeGCN on MI355X (gfx950). Inputs fp32, edge_index int32, output fp32.
// (Dtypes proven R1-R5: bf16-read NaN'd -> not bf16; probe_ei's atomic storm
//  -> odd words nonzero -> int32; R5 passed with fp32-convert + fp32-out.)
//
// Factorization:
//   P[n]  = x[n] @ (Wa - Wb) + b_edge   (Wa = W_edge[0:128], Wb = W_edge[128:256])
//   Q[n]  = x[n] @ Wb
//   msg(e)= relu(P[dst] + Q[src]);  edge_agg[d] = sum msg  (pull via CSR)
//   XA[d] = sum_{e->d} x[src]           (segment_sum commutes with @W_node)
//   nodes = relu(XA @ W_node + b_node); edges = relu(edge_agg @ W_ed + b_ed)
//   out   = sigmoid(relu([nodes|edges] @ W_f1 + b_f1) @ W_f2 + b_f2)
//
// R6 changes vs R5 (452 us):
//   - dtype probes DELETED (probe_ei alone was 73 us of same-address atomicOr)
//   - k_assign: wave-level shuffle prefix scan, 1 atomic/wave (was 50000
//     atomics to one address)
//   - convert_x + convert_w fused; memsets merged; k_final 4 waves/block
// ---------------------------------------------------------------------------

typedef short short8 __attribute__((ext_vector_type(8)));
typedef float f32x4 __attribute__((ext_vector_type(4)));
typedef float float4v __attribute__((ext_vector_type(4)));
typedef unsigned short us4 __attribute__((ext_vector_type(4)));
typedef unsigned short us2 __attribute__((ext_vector_type(2)));

__device__ inline float bf2f(unsigned short h) {
    union { unsigned int u; float f; } v;
    v.u = ((unsigned int)h) << 16;
    return v.f;
}
__device__ inline unsigned short f2bf(float f) {
    union { float f; unsigned int u; } v;
    v.f = f;
    unsigned int r = v.u + 0x7FFFu + ((v.u >> 16) & 1u);  // RNE
    return (unsigned short)(r >> 16);
}

// ---- convert: x (vectorized) + all weights -> canonical bf16 --------------
__global__ __launch_bounds__(256) void k_convert(
    const float* __restrict__ x, const float* __restrict__ W_edge,
    const float* __restrict__ W_node, const float* __restrict__ W_ed,
    const float* __restrict__ W_f1,
    unsigned short* __restrict__ xb, unsigned short* __restrict__ WE2,
    unsigned short* __restrict__ Wn, unsigned short* __restrict__ Wd,
    unsigned short* __restrict__ Wf1, int quads)  // quads = N*128/4
{
    int i = blockIdx.x * 256 + threadIdx.x;
    if (i < quads) {
        float4v v = ((const float4v*)x)[i];
        us4 o;
        for (int j = 0; j < 4; ++j) o[j] = f2bf(v[j]);
        ((us4*)xb)[i] = o;
        return;
    }
    int j = i - quads;
    if (j < 65536) {                          // WE2 [128][512] = [Wa-Wb | Wb]
        int k = j >> 9, c = j & 511;
        float v;
        if (c < 256) v = W_edge[k * 256 + c] - W_edge[(k + 128) * 256 + c];
        else         v = W_edge[(k + 128) * 256 + (c - 256)];
        WE2[j] = f2bf(v);
    } else if (j < 65536 + 32768) {           // Wn [128*256]
        int t = j - 65536;
        Wn[t] = f2bf(W_node[t]);
    } else if (j < 65536 + 65536) {           // Wd [256*128]
        int t = j - 65536 - 32768;
        Wd[t] = f2bf(W_ed[t]);
    } else if (j < 65536 + 65536 + 12288) {   // Wf1 [384*32]
        int t = j - 65536 - 65536;
        Wf1[t] = f2bf(W_f1[t]);
    }
}

// ---- CSR build ------------------------------------------------------------
__global__ void k_hist(const int* __restrict__ dst, int* __restrict__ deg,
                       int E, int N) {
    int i = blockIdx.x * 256 + threadIdx.x;
    if (i >= E) return;
    int d = dst[i];
    if ((unsigned)d < (unsigned)N) atomicAdd(&deg[d], 1);
}

// start[n] via wave-level exclusive scan + one atomicAdd per wave.
// Segment ORDER across waves is arbitrary; contents per node are exact.
__global__ __launch_bounds__(256) void k_assign(
    int* __restrict__ deg_cursor, int* __restrict__ startv,
    int* __restrict__ counter, int N)
{
    int n = blockIdx.x * 256 + threadIdx.x;
    int lane = threadIdx.x & 63;
    int d = (n < N) ? deg_cursor[n] : 0;
    int incl = d;
    for (int s = 1; s < 64; s <<= 1) {
        int t = __shfl_up(incl, s, 64);
        if (lane >= s) incl += t;
    }
    int total = __shfl(incl, 63, 64);
    int base = 0;
    if (lane == 63) base = atomicAdd(counter, total);
    base = __shfl(base, 63, 64);
    int s0 = base + incl - d;
    if (n < N) {
        startv[n] = s0;
        deg_cursor[n] = s0;   // becomes the scatter cursor
    }
}

__global__ void k_scatter(const int* __restrict__ src, const int* __restrict__ dst,
                          int* __restrict__ cursor, unsigned short* __restrict__ csr_src,
                          int E, int N) {
    int i = blockIdx.x * 256 + threadIdx.x;
    if (i >= E) return;
    int s = src[i], d = dst[i];
    if ((unsigned)d >= (unsigned)N || (unsigned)s >= (unsigned)N) return;
    int pos = atomicAdd(&cursor[d], 1);
    if ((unsigned)pos < (unsigned)E) csr_src[pos] = (unsigned short)s;
}

// ---- GEMM1: T = xb @ WE2  (P cols get +b_edge) ----------------------------
__global__ __launch_bounds__(512) void k_gemm1(
    const unsigned short* __restrict__ xb,     // [N][128] bf16
    const unsigned short* __restrict__ WE2,    // [128][512] bf16
    const float* __restrict__ b_edge,          // [256] fp32
    unsigned short* __restrict__ T,            // [N][512]
    int row_tiles)
{
    const int lane = threadIdx.x & 63;
    const int wave = threadIdx.x >> 6;
    const int quad = lane >> 4;
    const int col16 = lane & 15;
    const int strip = blockIdx.y * 8 + wave;    // 0..31
    const int col = strip * 16 + col16;         // 0..511

    float bias = (col < 256) ? b_edge[col] : 0.f;

    short8 bf[4];
    for (int ks = 0; ks < 4; ++ks) {
        short8 b;
        for (int j = 0; j < 8; ++j) {
            int k = ks * 32 + quad * 8 + j;
            b[j] = (short)WE2[k * 512 + col];
        }
        bf[ks] = b;
    }

    for (int t = 0; t < 8; ++t) {
        int tile = blockIdx.x * 8 + t;
        if (tile >= row_tiles) break;
        int r0 = tile * 16;
        f32x4 acc = {0.f, 0.f, 0.f, 0.f};
        const unsigned short* ap = xb + (size_t)(r0 + col16) * 128 + quad * 8;
        for (int ks = 0; ks < 4; ++ks) {
            short8 a = *(const short8*)(ap + ks * 32);
            acc = __builtin_amdgcn_mfma_f32_16x16x32_bf16(a, bf[ks], acc, 0, 0, 0);
        }
        int orow = r0 + quad * 4;
        for (int r = 0; r < 4; ++r)
            T[(size_t)(orow + r) * 512 + col] = f2bf(acc[r] + bias);
    }
}

// ---- Gather: one wave per node; EA over P slot, XA from xb ----------------
__global__ __launch_bounds__(256) void k_gather(
    unsigned short* __restrict__ T,          // [N][512]
    const unsigned short* __restrict__ xb,   // [N][128]
    unsigned short* __restrict__ XA,         // [N][128]
    const int* __restrict__ start, const int* __restrict__ endp,
    const unsigned short* __restrict__ csr_src, int N, int E)
{
    int wave = threadIdx.x >> 6;
    int lane = threadIdx.x & 63;
    int n = blockIdx.x * 4 + wave;
    if (n >= N) return;
    int c4 = lane * 4;
    int c2 = lane * 2;

    us4 pv = *(const us4*)(T + (size_t)n * 512 + c4);
    float p[4], aE[4] = {0, 0, 0, 0}, aX[2] = {0, 0};
    for (int j = 0; j < 4; ++j) p[j] = bf2f(pv[j]);

    int b = start[n], e = endp[n];
    if (b < 0) b = 0;
    if (e > E) e = E;
    for (int i = b; i < e; ++i) {
        int s = csr_src[i];
        if (s >= N) continue;
        const unsigned short* tb = T + (size_t)s * 512;
        us4 qv = *(const us4*)(tb + 256 + c4);
        us2 xv = *(const us2*)(xb + (size_t)s * 128 + c2);
        for (int j = 0; j < 4; ++j)
            aE[j] += fmaxf(p[j] + bf2f(qv[j]), 0.f);
        aX[0] += bf2f(xv[0]);
        aX[1] += bf2f(xv[1]);
    }
    us4 ev;
    for (int j = 0; j < 4; ++j) ev[j] = f2bf(aE[j]);
    *(us4*)(T + (size_t)n * 512 + c4) = ev;            // EA over own P: safe
    us2 xo; xo[0] = f2bf(aX[0]); xo[1] = f2bf(aX[1]);
    *(us2*)(XA + (size_t)n * 128 + c2) = xo;
}

// ---- GEMM2: edges = relu(EA @ Wd + b_ed) -> T cols 384..511 ---------------
__global__ __launch_bounds__(512) void k_gemm2(
    unsigned short* __restrict__ T,           // reads cols 0-255 (EA)
    const unsigned short* __restrict__ Wd,    // [256][128] bf16
    const float* __restrict__ b_ed,           // [128] fp32
    int row_tiles)
{
    const int lane = threadIdx.x & 63;
    const int wave = threadIdx.x >> 6;
    const int quad = lane >> 4;
    const int col16 = lane & 15;
    const int col = wave * 16 + col16;        // 0..127

    short8 bf[8];
    for (int ks = 0; ks < 8; ++ks) {
        short8 b;
        for (int j = 0; j < 8; ++j) {
            int k = ks * 32 + quad * 8 + j;
            b[j] = (short)Wd[k * 128 + col];
        }
        bf[ks] = b;
    }
    float bias = b_ed[col];

    for (int t = 0; t < 8; ++t) {
        int tile = blockIdx.x * 8 + t;
        if (tile >= row_tiles) break;
        int r0 = tile * 16;
        f32x4 acc = {0.f, 0.f, 0.f, 0.f};
        const unsigned short* ap = T + (size_t)(r0 + col16) * 512 + quad * 8;
        for (int ks = 0; ks < 8; ++ks) {
            short8 a = *(const short8*)(ap + ks * 32);
            acc = __builtin_amdgcn_mfma_f32_16x16x32_bf16(a, bf[ks], acc, 0, 0, 0);
        }
        int orow = r0 + quad * 4;
        for (int r = 0; r < 4; ++r)
            T[(size_t)(orow + r) * 512 + 384 + col] = f2bf(fmaxf(acc[r] + bias, 0.f));
    }
}

// ---- GEMM-node: nodes = relu(XA @ Wn + b_node) -> T cols 0..255 -----------
__global__ __launch_bounds__(512) void k_gemm_node(
    const unsigned short* __restrict__ XA,      // [N][128]
    const unsigned short* __restrict__ Wn,      // [128][256] bf16
    const float* __restrict__ b_node,           // [256] fp32
    unsigned short* __restrict__ T, int row_tiles)
{
    const int lane = threadIdx.x & 63;
    const int wave = threadIdx.x >> 6;
    const int quad = lane >> 4;
    const int col16 = lane & 15;
    const int strip = blockIdx.y * 8 + wave;    // 0..15
    const int col = strip * 16 + col16;         // 0..255

    short8 bf[4];
    for (int ks = 0; ks < 4; ++ks) {
        short8 b;
        for (int j = 0; j < 8; ++j) {
            int k = ks * 32 + quad * 8 + j;
            b[j] = (short)Wn[k * 256 + col];
        }
        bf[ks] = b;
    }
    float bias = b_node[col];

    for (int t = 0; t < 8; ++t) {
        int tile = blockIdx.x * 8 + t;
        if (tile >= row_tiles) break;
        int r0 = tile * 16;
        f32x4 acc = {0.f, 0.f, 0.f, 0.f};
        const unsigned short* ap = XA + (size_t)(r0 + col16) * 128 + quad * 8;
        for (int ks = 0; ks < 4; ++ks) {
            short8 a = *(const short8*)(ap + ks * 32);
            acc = __builtin_amdgcn_mfma_f32_16x16x32_bf16(a, bf[ks], acc, 0, 0, 0);
        }
        int orow = r0 + quad * 4;
        for (int r = 0; r < 4; ++r)
            T[(size_t)(orow + r) * 512 + col] = f2bf(fmaxf(acc[r] + bias, 0.f));
    }
}

// ---- Final: out = sigmoid(relu(h@W_f1+b_f1)@W_f2+b_f2), h=[nodes|edges] ---
// 4 waves/block, each wave 2 row-tiles. fp32 output.
__global__ __launch_bounds__(256) void k_final(
    const unsigned short* __restrict__ T,
    const unsigned short* __restrict__ Wf1,   // [384][32] bf16
    const float* __restrict__ b_f1,           // [32]
    const float* __restrict__ W_f2,           // [32]
    const float* __restrict__ b_f2,           // [1]
    float* __restrict__ out, int row_tiles)
{
    const int wave = threadIdx.x >> 6;
    const int lane = threadIdx.x & 63;
    const int quad = lane >> 4;
    const int col16 = lane & 15;

    short8 bfa[12], bfb[12];
    for (int ks = 0; ks < 12; ++ks) {
        short8 a, b;
        for (int j = 0; j < 8; ++j) {
            int k = ks * 32 + quad * 8 + j;
            a[j] = (short)Wf1[k * 32 + col16];
            b[j] = (short)Wf1[k * 32 + 16 + col16];
        }
        bfa[ks] = a; bfb[ks] = b;
    }
    float f1a = b_f1[col16], f1b = b_f1[16 + col16];
    float w2a = W_f2[col16], w2b = W_f2[16 + col16];
    float b2 = b_f2[0];

    for (int t = 0; t < 2; ++t) {
        int tile = blockIdx.x * 8 + wave * 2 + t;
        if (tile >= row_tiles) continue;
        int r0 = tile * 16;
        f32x4 acc0 = {0, 0, 0, 0}, acc1 = {0, 0, 0, 0};
        const unsigned short* ap = T + (size_t)(r0 + col16) * 512;
        for (int ks = 0; ks < 12; ++ks) {
            int off = (ks < 8) ? ks * 32 : ks * 32 + 128;  // nodes | edges slot
            short8 a = *(const short8*)(ap + off + quad * 8);
            acc0 = __builtin_amdgcn_mfma_f32_16x16x32_bf16(a, bfa[ks], acc0, 0, 0, 0);
            acc1 = __builtin_amdgcn_mfma_f32_16x16x32_bf16(a, bfb[ks], acc1, 0, 0, 0);
        }
        float s[4];
        for (int r = 0; r < 4; ++r)
            s[r] = fmaxf(acc0[r] + f1a, 0.f) * w2a + fmaxf(acc1[r] + f1b, 0.f) * w2b;
        for (int m = 1; m < 16; m <<= 1)
            for (int r = 0; r < 4; ++r) s[r] += __shfl_xor(s[r], m, 64);
        if (col16 == 0) {
            int orow = r0 + quad * 4;
            for (int r = 0; r < 4; ++r) {
                float v = s[r] + b2;
                out[orow + r] = 1.f / (1.f + __expf(-v));
            }
        }
    }
}

extern "C" void kernel_launch(void* const* d_in, const int* in_sizes, int n_in,
                              void* d_out, int out_size, void* d_ws, size_t ws_size,
                              hipStream_t stream) {
    const float* x      = (const float*)d_in[0];
    const int*   ei     = (const int*)d_in[1];
    // d_in[2] = e (unused)
    const float* W_node = (const float*)d_in[3];
    const float* b_node = (const float*)d_in[4];
    const float* W_edge = (const float*)d_in[5];
    const float* b_edge = (const float*)d_in[6];
    const float* W_ed   = (const float*)d_in[7];
    const float* b_ed   = (const float*)d_in[8];
    const float* W_f1   = (const float*)d_in[9];
    const float* b_f1   = (const float*)d_in[10];
    const float* W_f2   = (const float*)d_in[11];
    const float* b_f2   = (const float*)d_in[12];

    const int N = in_sizes[0] / 128;
    const int E = in_sizes[1] / 2;
    const int* src = ei;
    const int* dst = ei + E;

    char* ws = (char*)d_ws;
    size_t off = 0;
    auto alloc = [&](size_t bytes) { size_t o = off; off += (bytes + 255) & ~(size_t)255; return o; };
    unsigned short* xb  = (unsigned short*)(ws + alloc((size_t)N * 128 * 2));
    unsigned short* WE2 = (unsigned short*)(ws + alloc(128 * 512 * 2));
    unsigned short* Wn  = (unsigned short*)(ws + alloc(128 * 256 * 2));
    unsigned short* Wd  = (unsigned short*)(ws + alloc(256 * 128 * 2));
    unsigned short* Wf1 = (unsigned short*)(ws + alloc(384 * 32 * 2));
    unsigned short* T   = (unsigned short*)(ws + alloc((size_t)N * 512 * 2));
    unsigned short* XA  = (unsigned short*)(ws + alloc((size_t)N * 128 * 2));
    // deg_cursor and counter adjacent -> one memset
    int* deg_cursor     = (int*)(ws + alloc((size_t)N * 4 + 16));
    int* counter        = deg_cursor + N;
    int* startv         = (int*)(ws + alloc((size_t)N * 4));
    unsigned short* csr = (unsigned short*)(ws + alloc((size_t)E * 2));

    const int row_tiles  = (N + 15) / 16;
    const int row_groups = (row_tiles + 7) / 8;
    const int quads = N * 128 / 4;
    const int conv_items = quads + 65536 + 65536 + 12288;

    hipMemsetAsync(deg_cursor, 0, (size_t)N * 4 + 16, stream);
    k_convert<<<(conv_items + 255) / 256, 256, 0, stream>>>(
        x, W_edge, W_node, W_ed, W_f1, xb, WE2, Wn, Wd, Wf1, quads);
    k_hist<<<(E + 255) / 256, 256, 0, stream>>>(dst, deg_cursor, E, N);
    k_assign<<<(N + 255) / 256, 256, 0, stream>>>(deg_cursor, startv, counter, N);
    k_scatter<<<(E + 255) / 256, 256, 0, stream>>>(src, dst, deg_cursor, csr, E, N);
    k_gemm1<<<dim3(row_groups, 4), 512, 0, stream>>>(xb, WE2, b_edge, T, row_tiles);
    k_gather<<<(N + 3) / 4, 256, 0, stream>>>(T, xb, XA, startv, deg_cursor, csr, N, E);
    k_gemm2<<<row_groups, 512, 0, stream>>>(T, Wd, b_ed, row_tiles);
    k_gemm_node<<<dim3(row_groups, 2), 512, 0, stream>>>(XA, Wn, b_node, T, row_tiles);
    k_final<<<row_groups, 256, 0, stream>>>(T, Wf1, b_f1, W_f2, b_f2,
                                            (float*)d_out, row_tiles);
}

// Round 7
// 321.884 us; speedup vs baseline: 1.4040x; 1.1318x over previous
//
#include <hip/hip_runtime.h>
#include <stdint.h>

// ---------------------------------------------------------------------------
// EdgeNodeGCN on MI355X (gfx950). Inputs fp32, edge_index int32, output fp32.
// Factorization:
//   P[n]  = x[n] @ (Wa - Wb) + b_edge   (Wa = W_edge[0:128], Wb = W_edge[128:256])
//   Q[n]  = x[n] @ Wb
//   msg(e)= relu(P[dst] + Q[src]);  edge_agg[d] = sum msg  (pull via CSR)
//   XA[d] = sum_{e->d} x[src]           (segment_sum commutes with @W_node)
//   nodes = relu(XA @ W_node + b_node); edges = relu(edge_agg @ W_ed + b_ed)
//   out   = sigmoid(relu([nodes|edges] @ W_f1 + b_f1) @ W_f2 + b_f2)
//
// R7 vs R6 (364 us):
//   - gather: 2 edges/iter (half-wave each, 16B Q loads), 1-wave blocks
//     (kills max-of-4-degree block imbalance). R6: 64.6us @3TB/s, VALU 30%.
//   - dispatches 11 -> 6: memset folded into convert; scatter+gemm1 one
//     dispatch; gemm2+gemm_node+final fused into k_tail (saves ~77MB T
//     round-trip; per-wave LDS tile for C-layout -> A-layout transform).
// ---------------------------------------------------------------------------

typedef short short8 __attribute__((ext_vector_type(8)));
typedef float f32x4 __attribute__((ext_vector_type(4)));
typedef float float4v __attribute__((ext_vector_type(4)));
typedef unsigned short us8 __attribute__((ext_vector_type(8)));
typedef unsigned short us4 __attribute__((ext_vector_type(4)));

__device__ inline float bf2f(unsigned short h) {
    union { unsigned int u; float f; } v;
    v.u = ((unsigned int)h) << 16;
    return v.f;
}
__device__ inline unsigned short f2bf(float f) {
    union { float f; unsigned int u; } v;
    v.f = f;
    unsigned int r = v.u + 0x7FFFu + ((v.u >> 16) & 1u);  // RNE
    return (unsigned short)(r >> 16);
}

// ---- convert x + weights -> bf16, and zero deg/counter --------------------
__global__ __launch_bounds__(256) void k_convert(
    const float* __restrict__ x, const float* __restrict__ W_edge,
    const float* __restrict__ W_node, const float* __restrict__ W_ed,
    const float* __restrict__ W_f1,
    unsigned short* __restrict__ xb, unsigned short* __restrict__ WE2,
    unsigned short* __restrict__ Wn, unsigned short* __restrict__ Wd,
    unsigned short* __restrict__ Wf1, int* __restrict__ deg,
    int quads, int nzero)
{
    int i = blockIdx.x * 256 + threadIdx.x;
    if (i < quads) {
        float4v v = ((const float4v*)x)[i];
        us4 o;
        for (int j = 0; j < 4; ++j) o[j] = f2bf(v[j]);
        ((us4*)xb)[i] = o;
        return;
    }
    int j = i - quads;
    if (j < 65536) {                          // WE2 [128][512] = [Wa-Wb | Wb]
        int k = j >> 9, c = j & 511;
        float v;
        if (c < 256) v = W_edge[k * 256 + c] - W_edge[(k + 128) * 256 + c];
        else         v = W_edge[(k + 128) * 256 + (c - 256)];
        WE2[j] = f2bf(v);
    } else if (j < 65536 + 32768) {           // Wn [128*256]
        int t = j - 65536;
        Wn[t] = f2bf(W_node[t]);
    } else if (j < 65536 + 65536) {           // Wd [256*128]
        int t = j - 65536 - 32768;
        Wd[t] = f2bf(W_ed[t]);
    } else if (j < 143360) {                  // Wf1 [384*32]
        int t = j - 65536 - 65536;
        Wf1[t] = f2bf(W_f1[t]);
    } else {
        int t = j - 143360;
        if (t < nzero) deg[t] = 0;            // deg[N] + counter
    }
}

// ---- CSR build ------------------------------------------------------------
__global__ void k_hist(const int* __restrict__ dst, int* __restrict__ deg,
                       int E, int N) {
    int i = blockIdx.x * 256 + threadIdx.x;
    if (i >= E) return;
    int d = dst[i];
    if ((unsigned)d < (unsigned)N) atomicAdd(&deg[d], 1);
}

// start[n] via wave-level exclusive scan + one atomicAdd per wave.
__global__ __launch_bounds__(256) void k_assign(
    int* __restrict__ deg_cursor, int* __restrict__ startv,
    int* __restrict__ counter, int N)
{
    int n = blockIdx.x * 256 + threadIdx.x;
    int lane = threadIdx.x & 63;
    int d = (n < N) ? deg_cursor[n] : 0;
    int incl = d;
    for (int s = 1; s < 64; s <<= 1) {
        int t = __shfl_up(incl, s, 64);
        if (lane >= s) incl += t;
    }
    int total = __shfl(incl, 63, 64);
    int base = 0;
    if (lane == 63) base = atomicAdd(counter, total);
    base = __shfl(base, 63, 64);
    int s0 = base + incl - d;
    if (n < N) {
        startv[n] = s0;
        deg_cursor[n] = s0;   // becomes the scatter cursor
    }
}

// ---- fused dispatch: scatter (first S blocks) + GEMM1 (rest) --------------
__global__ __launch_bounds__(512) void k_sg(
    const int* __restrict__ src, const int* __restrict__ dst,
    int* __restrict__ cursor, unsigned short* __restrict__ csr_src,
    const unsigned short* __restrict__ xb,     // [N][128] bf16
    const unsigned short* __restrict__ WE2,    // [128][512] bf16
    const float* __restrict__ b_edge,          // [256] fp32
    unsigned short* __restrict__ T,            // [N][512]
    int E, int N, int row_tiles, int scat_blocks)
{
    if ((int)blockIdx.x < scat_blocks) {
        int i = blockIdx.x * 512 + threadIdx.x;
        if (i >= E) return;
        int s = src[i], d = dst[i];
        if ((unsigned)d >= (unsigned)N || (unsigned)s >= (unsigned)N) return;
        int pos = atomicAdd(&cursor[d], 1);
        if ((unsigned)pos < (unsigned)E) csr_src[pos] = (unsigned short)s;
        return;
    }
    int g = blockIdx.x - scat_blocks;          // 0 .. 4*row_groups-1
    int gx = g >> 2;                           // row group
    int gy = g & 3;                            // col quarter

    const int lane = threadIdx.x & 63;
    const int wave = threadIdx.x >> 6;
    const int quad = lane >> 4;
    const int col16 = lane & 15;
    const int strip = gy * 8 + wave;           // 0..31
    const int col = strip * 16 + col16;        // 0..511

    float bias = (col < 256) ? b_edge[col] : 0.f;

    short8 bf[4];
    for (int ks = 0; ks < 4; ++ks) {
        short8 b;
        for (int j = 0; j < 8; ++j) {
            int k = ks * 32 + quad * 8 + j;
            b[j] = (short)WE2[k * 512 + col];
        }
        bf[ks] = b;
    }

    for (int t = 0; t < 8; ++t) {
        int tile = gx * 8 + t;
        if (tile >= row_tiles) break;
        int r0 = tile * 16;
        f32x4 acc = {0.f, 0.f, 0.f, 0.f};
        const unsigned short* ap = xb + (size_t)(r0 + col16) * 128 + quad * 8;
        for (int ks = 0; ks < 4; ++ks) {
            short8 a = *(const short8*)(ap + ks * 32);
            acc = __builtin_amdgcn_mfma_f32_16x16x32_bf16(a, bf[ks], acc, 0, 0, 0);
        }
        int orow = r0 + quad * 4;
        for (int r = 0; r < 4; ++r)
            T[(size_t)(orow + r) * 512 + col] = f2bf(acc[r] + bias);
    }
}

// ---- Gather: one wave per node, 2 edges per iteration ---------------------
// lanes 0-31 handle edge i, lanes 32-63 edge i+1; halves combined via shfl.
__global__ __launch_bounds__(64) void k_gather(
    unsigned short* __restrict__ T,          // [N][512]: P|Q -> EA over P
    const unsigned short* __restrict__ xb,   // [N][128]
    unsigned short* __restrict__ XA,         // [N][128]
    const int* __restrict__ start, const int* __restrict__ endp,
    const unsigned short* __restrict__ csr_src, int N, int E)
{
    int n = blockIdx.x;
    if (n >= N) return;
    int lane = threadIdx.x;
    int half = lane >> 5;
    int c = lane & 31;
    int c8 = c * 8;
    int c4 = c * 4;

    us8 pv = *(const us8*)(T + (size_t)n * 512 + c8);
    float p[8];
    for (int j = 0; j < 8; ++j) p[j] = bf2f(pv[j]);
    float aE[8] = {0, 0, 0, 0, 0, 0, 0, 0};
    float aX[4] = {0, 0, 0, 0};

    int b = start[n], e = endp[n];
    if (b < 0) b = 0;
    if (e > E) e = E;
    for (int i = b; i < e; i += 2) {
        int idx = i + half;
        float vm = (idx < e) ? 1.f : 0.f;
        if (idx >= e) idx = e - 1;
        int s = csr_src[idx];                 // u16 < 65536; poison 0xAAAA < N*? in-bounds
        const unsigned short* tb = T + (size_t)s * 512;
        us8 qv = *(const us8*)(tb + 256 + c8);
        us4 xv = *(const us4*)(xb + (size_t)s * 128 + c4);
        for (int j = 0; j < 8; ++j)
            aE[j] += vm * fmaxf(p[j] + bf2f(qv[j]), 0.f);
        for (int j = 0; j < 4; ++j)
            aX[j] += vm * bf2f(xv[j]);
    }
    for (int j = 0; j < 8; ++j) aE[j] += __shfl_xor(aE[j], 32, 64);
    for (int j = 0; j < 4; ++j) aX[j] += __shfl_xor(aX[j], 32, 64);
    if (half == 0) {
        us8 ev;
        for (int j = 0; j < 8; ++j) ev[j] = f2bf(aE[j]);
        *(us8*)(T + (size_t)n * 512 + c8) = ev;       // EA over own P slot: safe
        us4 xo;
        for (int j = 0; j < 4; ++j) xo[j] = f2bf(aX[j]);
        *(us4*)(XA + (size_t)n * 128 + c4) = xo;
    }
}

// ---- Fused tail: nodes/edges GEMMs + final MLP + sigmoid ------------------
// One wave per 16-row tile. C-layout -> A-layout via per-wave LDS tile
// [16][392] bf16 (pad 392: 2-way LDS aliasing only). No __syncthreads
// (wave-local LDS; in-wave DS ordering via compiler lgkmcnt).
__global__ __launch_bounds__(256) void k_tail(
    const unsigned short* __restrict__ T,    // EA in cols 0-255
    const unsigned short* __restrict__ XA,   // [N][128]
    const unsigned short* __restrict__ Wn,   // [128][256]
    const unsigned short* __restrict__ Wd,   // [256][128]
    const unsigned short* __restrict__ Wf1,  // [384][32]
    const float* __restrict__ b_node, const float* __restrict__ b_ed,
    const float* __restrict__ b_f1, const float* __restrict__ W_f2,
    const float* __restrict__ b_f2,
    float* __restrict__ out, int N, int row_tiles)
{
    __shared__ unsigned short hs[4][16 * 392];
    const int wave = threadIdx.x >> 6;
    const int lane = threadIdx.x & 63;
    const int quad = lane >> 4;
    const int col16 = lane & 15;
    int tile = blockIdx.x * 4 + wave;
    if (tile >= row_tiles) return;            // no barriers below: safe
    int r0 = tile * 16;
    unsigned short* hw = &hs[wave][0];

    int arow = r0 + col16;
    if (arow >= N) arow = N - 1;              // clamp A-loads; stores guarded

    // nodes = relu(XA @ Wn + b_node) -> LDS cols 0-255
    short8 ax[4];
    {
        const unsigned short* xap = XA + (size_t)arow * 128 + quad * 8;
        for (int ks = 0; ks < 4; ++ks) ax[ks] = *(const short8*)(xap + ks * 32);
    }
    for (int cs = 0; cs < 16; ++cs) {
        int col = cs * 16 + col16;
        f32x4 acc = {0.f, 0.f, 0.f, 0.f};
        for (int ks = 0; ks < 4; ++ks) {
            short8 b;
            for (int j = 0; j < 8; ++j)
                b[j] = (short)Wn[(ks * 32 + quad * 8 + j) * 256 + col];
            acc = __builtin_amdgcn_mfma_f32_16x16x32_bf16(ax[ks], b, acc, 0, 0, 0);
        }
        float bias = b_node[col];
        for (int r = 0; r < 4; ++r)
            hw[(quad * 4 + r) * 392 + col] = f2bf(fmaxf(acc[r] + bias, 0.f));
    }

    // edges = relu(EA @ Wd + b_ed) -> LDS cols 256-383
    short8 ae[8];
    {
        const unsigned short* eap = T + (size_t)arow * 512 + quad * 8;
        for (int ks = 0; ks < 8; ++ks) ae[ks] = *(const short8*)(eap + ks * 32);
    }
    for (int cs = 0; cs < 8; ++cs) {
        int col = cs * 16 + col16;
        f32x4 acc = {0.f, 0.f, 0.f, 0.f};
        for (int ks = 0; ks < 8; ++ks) {
            short8 b;
            for (int j = 0; j < 8; ++j)
                b[j] = (short)Wd[(ks * 32 + quad * 8 + j) * 128 + col];
            acc = __builtin_amdgcn_mfma_f32_16x16x32_bf16(ae[ks], b, acc, 0, 0, 0);
        }
        float bias = b_ed[col];
        for (int r = 0; r < 4; ++r)
            hw[(quad * 4 + r) * 392 + 256 + col] = f2bf(fmaxf(acc[r] + bias, 0.f));
    }

    // h @ Wf1 (K=384, two 16-col halves), relu, @W_f2, sigmoid
    f32x4 acc0 = {0.f, 0.f, 0.f, 0.f}, acc1 = {0.f, 0.f, 0.f, 0.f};
    const unsigned short* hp = hw + col16 * 392;
    for (int ks = 0; ks < 12; ++ks) {
        short8 a = *(const short8*)(hp + ks * 32 + quad * 8);
        short8 ba, bb;
        for (int j = 0; j < 8; ++j) {
            int k = ks * 32 + quad * 8 + j;
            ba[j] = (short)Wf1[k * 32 + col16];
            bb[j] = (short)Wf1[k * 32 + 16 + col16];
        }
        acc0 = __builtin_amdgcn_mfma_f32_16x16x32_bf16(a, ba, acc0, 0, 0, 0);
        acc1 = __builtin_amdgcn_mfma_f32_16x16x32_bf16(a, bb, acc1, 0, 0, 0);
    }
    float f1a = b_f1[col16], f1b = b_f1[16 + col16];
    float w2a = W_f2[col16], w2b = W_f2[16 + col16];
    float b2 = b_f2[0];
    float s[4];
    for (int r = 0; r < 4; ++r)
        s[r] = fmaxf(acc0[r] + f1a, 0.f) * w2a + fmaxf(acc1[r] + f1b, 0.f) * w2b;
    for (int m = 1; m < 16; m <<= 1)
        for (int r = 0; r < 4; ++r) s[r] += __shfl_xor(s[r], m, 64);
    if (col16 == 0) {
        int orow = r0 + quad * 4;
        for (int r = 0; r < 4; ++r) {
            if (orow + r < N) {
                float v = s[r] + b2;
                out[orow + r] = 1.f / (1.f + __expf(-v));
            }
        }
    }
}

extern "C" void kernel_launch(void* const* d_in, const int* in_sizes, int n_in,
                              void* d_out, int out_size, void* d_ws, size_t ws_size,
                              hipStream_t stream) {
    const float* x      = (const float*)d_in[0];
    const int*   ei     = (const int*)d_in[1];
    // d_in[2] = e (unused)
    const float* W_node = (const float*)d_in[3];
    const float* b_node = (const float*)d_in[4];
    const float* W_edge = (const float*)d_in[5];
    const float* b_edge = (const float*)d_in[6];
    const float* W_ed   = (const float*)d_in[7];
    const float* b_ed   = (const float*)d_in[8];
    const float* W_f1   = (const float*)d_in[9];
    const float* b_f1   = (const float*)d_in[10];
    const float* W_f2   = (const float*)d_in[11];
    const float* b_f2   = (const float*)d_in[12];

    const int N = in_sizes[0] / 128;
    const int E = in_sizes[1] / 2;
    const int* src = ei;
    const int* dst = ei + E;

    char* ws = (char*)d_ws;
    size_t off = 0;
    auto alloc = [&](size_t bytes) { size_t o = off; off += (bytes + 255) & ~(size_t)255; return o; };
    unsigned short* xb  = (unsigned short*)(ws + alloc((size_t)N * 128 * 2));
    unsigned short* WE2 = (unsigned short*)(ws + alloc(128 * 512 * 2));
    unsigned short* Wn  = (unsigned short*)(ws + alloc(128 * 256 * 2));
    unsigned short* Wd  = (unsigned short*)(ws + alloc(256 * 128 * 2));
    unsigned short* Wf1 = (unsigned short*)(ws + alloc(384 * 32 * 2));
    unsigned short* T   = (unsigned short*)(ws + alloc((size_t)N * 512 * 2));
    unsigned short* XA  = (unsigned short*)(ws + alloc((size_t)N * 128 * 2));
    int* deg_cursor     = (int*)(ws + alloc((size_t)N * 4 + 16));
    int* counter        = deg_cursor + N;
    int* startv         = (int*)(ws + alloc((size_t)N * 4));
    unsigned short* csr = (unsigned short*)(ws + alloc((size_t)E * 2));

    const int row_tiles   = (N + 15) / 16;
    const int row_groups  = (row_tiles + 7) / 8;
    const int quads       = N * 128 / 4;
    const int nzero       = N + 4;
    const int conv_items  = quads + 143360 + nzero;
    const int scat_blocks = (E + 511) / 512;
    const int gemm_blocks = row_groups * 4;

    k_convert<<<(conv_items + 255) / 256, 256, 0, stream>>>(
        x, W_edge, W_node, W_ed, W_f1, xb, WE2, Wn, Wd, Wf1, deg_cursor,
        quads, nzero);
    k_hist<<<(E + 255) / 256, 256, 0, stream>>>(dst, deg_cursor, E, N);
    k_assign<<<(N + 255) / 256, 256, 0, stream>>>(deg_cursor, startv, counter, N);
    k_sg<<<scat_blocks + gemm_blocks, 512, 0, stream>>>(
        src, dst, deg_cursor, csr, xb, WE2, b_edge, T, E, N, row_tiles, scat_blocks);
    k_gather<<<N, 64, 0, stream>>>(T, xb, XA, startv, deg_cursor, csr, N, E);
    k_tail<<<(row_tiles + 3) / 4, 256, 0, stream>>>(
        T, XA, Wn, Wd, Wf1, b_node, b_ed, b_f1, W_f2, b_f2,
        (float*)d_out, N, row_tiles);
}